// Round 7
// baseline (263.759 us; speedup 1.0000x reference)
//
#include <hip/hip_runtime.h>
#include <hip/hip_bf16.h>

// Problem constants
#define N_NODES 50000
#define E_EDGES 800000
#define D_IN    256
#define H_HEADS 4
#define HF      128          // H*F
#define NEG_SLOPE 0.2f
#define SCAN_BLOCKS ((N_NODES + 255) / 256)   // 196
#define HIST_BLOCKS (E_EDGES / 256)           // 3125
#define PREP_BLOCKS 128                       // 32768 W elems / 256
#define FILL_BLOCKS (E_EDGES / 256)           // 3125
#define GEMM_BLOCKS ((N_NODES + 63) / 64)     // 782

typedef __attribute__((ext_vector_type(8))) short bf16x8;   // 8 bf16 = 4 VGPRs
typedef __attribute__((ext_vector_type(4))) float f32x4;

// ---------------------------------------------------------------------------
// F1: fat kernel = [hist: 3125 blocks] + [prepW: 128 blocks].
// hist first (it feeds scan -> fill, the critical path).
// ---------------------------------------------------------------------------
__global__ __launch_bounds__(256) void k_hist_prep(const int* __restrict__ dst,
                                                   unsigned* __restrict__ cnt,
                                                   const float* __restrict__ W,
                                                   __hip_bfloat16* __restrict__ Wt) {
    const int b = blockIdx.x;
    if (b < HIST_BLOCKS) {
        const int g = b * 256 + threadIdx.x;        // over E (exact)
        atomicAdd(&cnt[dst[g]], 1u);
    } else {
        const int g = (b - HIST_BLOCKS) * 256 + threadIdx.x;  // over 32768
        const int n = g >> 8;
        const int k = g & 255;
        Wt[n * D_IN + k] = __float2bfloat16(W[k * HF + n]);
    }
}

// ---------------------------------------------------------------------------
// merged scan: block b reduces cnt[0..b*256) cooperatively, then LDS-scans
// its own 256 elems.
// ---------------------------------------------------------------------------
__global__ __launch_bounds__(256) void k_scan(const unsigned* __restrict__ cnt,
                                              unsigned* __restrict__ off) {
    __shared__ unsigned s[256];
    const int t = threadIdx.x;
    const int b = blockIdx.x;
    const int base = b * 256;

    unsigned part = 0;
    #pragma unroll 4
    for (int i = t; i < base; i += 256) part += cnt[i];
    s[t] = part;
    __syncthreads();
    #pragma unroll
    for (int o = 128; o > 0; o >>= 1) {
        if (t < o) s[t] += s[t + o];
        __syncthreads();
    }
    const unsigned pre = s[0];
    __syncthreads();

    const int g = base + t;
    const unsigned x = (g < N_NODES) ? cnt[g] : 0u;
    s[t] = x;
    __syncthreads();
    unsigned inc = x;
    #pragma unroll
    for (int o = 1; o < 256; o <<= 1) {
        const unsigned v = (t >= o) ? s[t - o] : 0u;
        __syncthreads();
        inc += v;
        s[t] = inc;
        __syncthreads();
    }
    if (g < N_NODES) off[g] = pre + inc - x;   // exclusive
}

// ---------------------------------------------------------------------------
// F3: fat kernel = [fill: 3125 blocks] + [gemm: 782 blocks].
// fill is latency/write-drain bound (VALU 0.3%); gemm is MFMA/LDS bound —
// co-residency hides gemm's time inside fill's memory-drain window.
// fill: perm[atomicAdd(&off[dst],1)] = src  (off: start -> end offsets).
// gemm: hW = h @ Wt (bf16 MFMA, fp32 acc) + fused el/er epilogue.
// ---------------------------------------------------------------------------
__global__ __launch_bounds__(256) void k_fill_gemm(const int* __restrict__ src,
                                                   const int* __restrict__ dst,
                                                   unsigned* __restrict__ off,
                                                   unsigned* __restrict__ perm,
                                                   const float* __restrict__ h,
                                                   const __hip_bfloat16* __restrict__ Wt,
                                                   const float* __restrict__ lw,
                                                   const float* __restrict__ lb,
                                                   const float* __restrict__ rw,
                                                   const float* __restrict__ rb,
                                                   __hip_bfloat16* __restrict__ hW,
                                                   float* __restrict__ el,
                                                   float* __restrict__ er) {
    __shared__ __hip_bfloat16 As[64][72];
    __shared__ __hip_bfloat16 Bs[128][72];

    if (blockIdx.x < FILL_BLOCKS) {
        // ---- fill role ----
        const int g = blockIdx.x * 256 + threadIdx.x;   // over E (exact)
        const unsigned p = atomicAdd(&off[dst[g]], 1u);
        perm[p] = (unsigned)src[g];
        return;
    }

    // ---- gemm role ----
    const int t    = threadIdx.x;
    const int r0   = (blockIdx.x - FILL_BLOCKS) * 64;
    const int wave = t >> 6;
    const int lane = t & 63;
    const int l16  = lane & 15;
    const int quad = lane >> 4;

    f32x4 acc[8] = {};

    for (int k0 = 0; k0 < D_IN; k0 += 64) {
        {   // stage A: 64 rows x 64 k, fp32 -> bf16
            const int row  = t >> 2;
            const int koff = (t & 3) * 16;
            const int n    = r0 + row;
            float v[16];
            if (n < N_NODES) {
                const float* p = h + (size_t)n * D_IN + k0 + koff;
                *(float4*)&v[0]  = ((const float4*)p)[0];
                *(float4*)&v[4]  = ((const float4*)p)[1];
                *(float4*)&v[8]  = ((const float4*)p)[2];
                *(float4*)&v[12] = ((const float4*)p)[3];
            } else {
                #pragma unroll
                for (int i = 0; i < 16; ++i) v[i] = 0.f;
            }
            __hip_bfloat16 b[16];
            #pragma unroll
            for (int i = 0; i < 16; ++i) b[i] = __float2bfloat16(v[i]);
            *(uint4*)&As[row][koff]     = ((uint4*)b)[0];
            *(uint4*)&As[row][koff + 8] = ((uint4*)b)[1];
        }
        {   // stage B: 128 n-rows x 64 k from Wt (bf16)
            const int n    = t >> 1;
            const int koff = (t & 1) * 32;
            const uint4* p = (const uint4*)(Wt + n * D_IN + k0 + koff);
            uint4 b0 = p[0], b1 = p[1], b2 = p[2], b3 = p[3];
            uint4* q = (uint4*)&Bs[n][koff];
            q[0] = b0; q[1] = b1; q[2] = b2; q[3] = b3;
        }
        __syncthreads();

        #pragma unroll
        for (int ks = 0; ks < 2; ++ks) {
            const bf16x8 af = *(const bf16x8*)&As[wave * 16 + l16][ks * 32 + quad * 8];
            #pragma unroll
            for (int nt = 0; nt < 8; ++nt) {
                const bf16x8 bfg = *(const bf16x8*)&Bs[nt * 16 + l16][ks * 32 + quad * 8];
                acc[nt] = __builtin_amdgcn_mfma_f32_16x16x32_bf16(af, bfg, acc[nt], 0, 0, 0);
            }
        }
        __syncthreads();
    }

    // epilogue: lane holds col = nt*16+l16, rows mbase+0..3.
    const int mbase = r0 + wave * 16 + quad * 4;
    #pragma unroll
    for (int nt = 0; nt < 8; ++nt) {
        #pragma unroll
        for (int r = 0; r < 4; ++r) {
            const int m = mbase + r;
            if (m < N_NODES)
                hW[(size_t)m * HF + nt * 16 + l16] = __float2bfloat16(acc[nt][r]);
        }
    }

    const float lwv0 = lw[l16], lwv1 = lw[l16 + 16];
    const float rwv0 = rw[l16], rwv1 = rw[l16 + 16];
    const float lb0 = lb[0], rb0 = rb[0];
    #pragma unroll
    for (int r = 0; r < 4; ++r) {
        const int m = mbase + r;
        float el4[4], er4[4];
        #pragma unroll
        for (int hh = 0; hh < 4; ++hh) {
            float pl = acc[2 * hh][r] * lwv0 + acc[2 * hh + 1][r] * lwv1;
            float pr = acc[2 * hh][r] * rwv0 + acc[2 * hh + 1][r] * rwv1;
            #pragma unroll
            for (int o = 1; o < 16; o <<= 1) {
                pl += __shfl_xor(pl, o);
                pr += __shfl_xor(pr, o);
            }
            el4[hh] = pl + lb0;
            er4[hh] = pr + rb0;
        }
        if (l16 == 0 && m < N_NODES) {
            *(float4*)&el[m * H_HEADS] = make_float4(el4[0], el4[1], el4[2], el4[3]);
            *(float4*)&er[m * H_HEADS] = make_float4(er4[0], er4[1], er4[2], er4[3]);
        }
    }
}

// ---------------------------------------------------------------------------
// K5: per-node softmax + weighted gather-sum. Wave-per-node (4 nodes/block);
// lane handles 2 features via one bf16x2 load. No max pass (logits < ~8,
// fp32 exp safe; alpha identical).
// ---------------------------------------------------------------------------
__global__ __launch_bounds__(256) void k_aggregate(const __hip_bfloat16* __restrict__ hW,
                                                   const float* __restrict__ el,
                                                   const float* __restrict__ er,
                                                   const unsigned* __restrict__ off_end,
                                                   const unsigned* __restrict__ perm,
                                                   const float* __restrict__ bias,
                                                   float* __restrict__ out) {
    const int wave = threadIdx.x >> 6;
    const int lane = threadIdx.x & 63;
    const int n    = blockIdx.x * 4 + wave;        // 12500*4 = 50000 exact
    const int hh   = lane >> 4;
    const unsigned beg = (n == 0) ? 0u : off_end[n - 1];
    const unsigned end = off_end[n];
    const float eld = el[n * H_HEADS + hh];
    const unsigned* hWu = (const unsigned*)hW;     // bf16x2 view

    float a0 = 0.f, a1 = 0.f, denom = 0.f;
    unsigned j = beg;
    for (; j + 4 <= end; j += 4) {
        int s[4];
        #pragma unroll
        for (int u = 0; u < 4; ++u) s[u] = (int)perm[j + u];
        unsigned g2[4];
        float e4[4];
        #pragma unroll
        for (int u = 0; u < 4; ++u) {
            g2[u] = hWu[(size_t)s[u] * (HF / 2) + lane];
            e4[u] = er[s[u] * H_HEADS + hh];
        }
        #pragma unroll
        for (int u = 0; u < 4; ++u) {
            float v = e4[u] + eld;
            v = (v >= 0.f) ? v : NEG_SLOPE * v;
            const float p = __expf(v);
            denom += p;
            a0 += p * __uint_as_float(g2[u] << 16);
            a1 += p * __uint_as_float(g2[u] & 0xFFFF0000u);
        }
    }
    for (; j < end; ++j) {
        const int si = (int)perm[j];
        const unsigned g2 = hWu[(size_t)si * (HF / 2) + lane];
        float v = er[si * H_HEADS + hh] + eld;
        v = (v >= 0.f) ? v : NEG_SLOPE * v;
        const float p = __expf(v);
        denom += p;
        a0 += p * __uint_as_float(g2 << 16);
        a1 += p * __uint_as_float(g2 & 0xFFFF0000u);
    }
    const float inv = (end > beg) ? 1.f / denom : 0.f;
    const float2 bv = *(const float2*)&bias[lane * 2];
    float2 o2 = make_float2(a0 * inv + bv.x, a1 * inv + bv.y);
    *(float2*)&out[(size_t)n * HF + lane * 2] = o2;
}

// ---------------------------------------------------------------------------
// launch — ws (float units): el 0 / er 200k / cnt 400k / off 450k /
// perm 500k / Wt 1300k / hW 1320k..4520k  => 18.1 MB (ws-safe).
// 4 kernels + 1 memset node (was 6+1). Chain A (prepW->gemm) overlapped
// into chain B (hist->scan->fill) via fat kernels.
// ---------------------------------------------------------------------------
extern "C" void kernel_launch(void* const* d_in, const int* in_sizes, int n_in,
                              void* d_out, int out_size, void* d_ws, size_t ws_size,
                              hipStream_t stream) {
    const float* h    = (const float*)d_in[0];
    const float* W    = (const float*)d_in[1];
    const float* lw   = (const float*)d_in[2];
    const float* lb   = (const float*)d_in[3];
    const float* rw   = (const float*)d_in[4];
    const float* rb   = (const float*)d_in[5];
    const float* bias = (const float*)d_in[6];
    const int*   src  = (const int*)d_in[7];
    const int*   dst  = (const int*)d_in[8];
    float* out = (float*)d_out;

    float*    ws   = (float*)d_ws;
    float*    el   = ws;                           // 200,000 f
    float*    er   = ws + 200000;                  // 200,000 f
    unsigned* cnt  = (unsigned*)(ws + 400000);     //  50,000 u32
    unsigned* off  = (unsigned*)(ws + 450000);     //  50,000 u32
    unsigned* perm = (unsigned*)(ws + 500000);     // 800,000 u32
    __hip_bfloat16* Wt = (__hip_bfloat16*)(ws + 1300000);  // 32,768 bf16
    __hip_bfloat16* hW = (__hip_bfloat16*)(ws + 1320000);  // 6.4M bf16

    hipMemsetAsync(cnt, 0, N_NODES * sizeof(unsigned), stream);
    k_hist_prep<<<HIST_BLOCKS + PREP_BLOCKS, 256, 0, stream>>>(dst, cnt, W, Wt);
    k_scan<<<SCAN_BLOCKS, 256, 0, stream>>>(cnt, off);
    k_fill_gemm<<<FILL_BLOCKS + GEMM_BLOCKS, 256, 0, stream>>>(
        src, dst, off, perm, h, Wt, lw, lb, rw, rb, hW, el, er);
    k_aggregate<<<N_NODES / 4, 256, 0, stream>>>(hW, el, er, off, perm, bias, out);
}

// Round 8
// 249.170 us; speedup vs baseline: 1.0586x; 1.0586x over previous
//
#include <hip/hip_runtime.h>
#include <hip/hip_bf16.h>

// Problem constants
#define N_NODES 50000
#define E_EDGES 800000
#define D_IN    256
#define H_HEADS 4
#define HF      128          // H*F
#define NEG_SLOPE 0.2f
#define SCAN_BLOCKS ((N_NODES + 255) / 256)   // 196
#define HIST_BLOCKS (E_EDGES / 256)           // 3125
#define PREP_BLOCKS 128                       // 32768 W elems / 256
#define FILL_PASSES 8
#define NODES_PER_PASS (N_NODES / FILL_PASSES)  // 6250

typedef __attribute__((ext_vector_type(8))) short bf16x8;   // 8 bf16 = 4 VGPRs
typedef __attribute__((ext_vector_type(4))) float f32x4;

// ---------------------------------------------------------------------------
// F1: fat kernel = [hist: 3125 blocks] + [prepW: 128 blocks]. No LDS in
// either role (grid-fusion is safe here, unlike the R7 fill+gemm mistake).
// ---------------------------------------------------------------------------
__global__ __launch_bounds__(256) void k_hist_prep(const int* __restrict__ dst,
                                                   unsigned* __restrict__ cnt,
                                                   const float* __restrict__ W,
                                                   __hip_bfloat16* __restrict__ Wt) {
    const int b = blockIdx.x;
    if (b < HIST_BLOCKS) {
        const int g = b * 256 + threadIdx.x;        // over E (exact)
        atomicAdd(&cnt[dst[g]], 1u);
    } else {
        const int g = (b - HIST_BLOCKS) * 256 + threadIdx.x;  // over 32768
        const int n = g >> 8;
        const int k = g & 255;
        Wt[n * D_IN + k] = __float2bfloat16(W[k * HF + n]);
    }
}

// ---------------------------------------------------------------------------
// merged scan: block b reduces cnt[0..b*256) cooperatively, then LDS-scans
// its own 256 elems.
// ---------------------------------------------------------------------------
__global__ __launch_bounds__(256) void k_scan(const unsigned* __restrict__ cnt,
                                              unsigned* __restrict__ off) {
    __shared__ unsigned s[256];
    const int t = threadIdx.x;
    const int b = blockIdx.x;
    const int base = b * 256;

    unsigned part = 0;
    #pragma unroll 4
    for (int i = t; i < base; i += 256) part += cnt[i];
    s[t] = part;
    __syncthreads();
    #pragma unroll
    for (int o = 128; o > 0; o >>= 1) {
        if (t < o) s[t] += s[t + o];
        __syncthreads();
    }
    const unsigned pre = s[0];
    __syncthreads();

    const int g = base + t;
    const unsigned x = (g < N_NODES) ? cnt[g] : 0u;
    s[t] = x;
    __syncthreads();
    unsigned inc = x;
    #pragma unroll
    for (int o = 1; o < 256; o <<= 1) {
        const unsigned v = (t >= o) ? s[t - o] : 0u;
        __syncthreads();
        inc += v;
        s[t] = inc;
        __syncthreads();
    }
    if (g < N_NODES) off[g] = pre + inc - x;   // exclusive
}

// ---------------------------------------------------------------------------
// K_fill: dst-range multi-pass scatter. Grid = 8 passes x 3125 chunks;
// pass = blockIdx/3125 handles dst in [pass*6250, (pass+1)*6250).
// Blocks dispatch ~in blockIdx order, so at any moment the live perm
// write-window is ~400 KB -> L2-resident -> full-line writebacks (fixes the
// 53 MB partial-line writeback that made single-pass fill 60 us).
// ---------------------------------------------------------------------------
__global__ __launch_bounds__(256) void k_fill(const int* __restrict__ src,
                                              const int* __restrict__ dst,
                                              unsigned* __restrict__ off,
                                              unsigned* __restrict__ perm) {
    const int pass  = blockIdx.x / HIST_BLOCKS;
    const int chunk = blockIdx.x - pass * HIST_BLOCKS;
    const int g = chunk * 256 + threadIdx.x;        // over E (exact)
    const int d = dst[g];
    const int lo = pass * NODES_PER_PASS;
    if ((unsigned)(d - lo) < (unsigned)NODES_PER_PASS) {
        const unsigned p = atomicAdd(&off[d], 1u);
        perm[p] = (unsigned)src[g];
    }
}

// ---------------------------------------------------------------------------
// K1: hW = h @ Wt via bf16 MFMA (16x16x32), fp32 acc, bf16 out; fused el/er
// epilogue from fp32 accumulators. Block 256 = 4 waves; tile 64x128; K by 64.
// ---------------------------------------------------------------------------
__global__ __launch_bounds__(256) void k_gemm(const float* __restrict__ h,
                                              const __hip_bfloat16* __restrict__ Wt,
                                              const float* __restrict__ lw,
                                              const float* __restrict__ lb,
                                              const float* __restrict__ rw,
                                              const float* __restrict__ rb,
                                              __hip_bfloat16* __restrict__ hW,
                                              float* __restrict__ el,
                                              float* __restrict__ er) {
    __shared__ __hip_bfloat16 As[64][72];
    __shared__ __hip_bfloat16 Bs[128][72];
    const int t    = threadIdx.x;
    const int r0   = blockIdx.x * 64;
    const int wave = t >> 6;
    const int lane = t & 63;
    const int l16  = lane & 15;
    const int quad = lane >> 4;

    f32x4 acc[8] = {};

    for (int k0 = 0; k0 < D_IN; k0 += 64) {
        {   // stage A: 64 rows x 64 k, fp32 -> bf16
            const int row  = t >> 2;
            const int koff = (t & 3) * 16;
            const int n    = r0 + row;
            float v[16];
            if (n < N_NODES) {
                const float* p = h + (size_t)n * D_IN + k0 + koff;
                *(float4*)&v[0]  = ((const float4*)p)[0];
                *(float4*)&v[4]  = ((const float4*)p)[1];
                *(float4*)&v[8]  = ((const float4*)p)[2];
                *(float4*)&v[12] = ((const float4*)p)[3];
            } else {
                #pragma unroll
                for (int i = 0; i < 16; ++i) v[i] = 0.f;
            }
            __hip_bfloat16 b[16];
            #pragma unroll
            for (int i = 0; i < 16; ++i) b[i] = __float2bfloat16(v[i]);
            *(uint4*)&As[row][koff]     = ((uint4*)b)[0];
            *(uint4*)&As[row][koff + 8] = ((uint4*)b)[1];
        }
        {   // stage B: 128 n-rows x 64 k from Wt (bf16)
            const int n    = t >> 1;
            const int koff = (t & 1) * 32;
            const uint4* p = (const uint4*)(Wt + n * D_IN + k0 + koff);
            uint4 b0 = p[0], b1 = p[1], b2 = p[2], b3 = p[3];
            uint4* q = (uint4*)&Bs[n][koff];
            q[0] = b0; q[1] = b1; q[2] = b2; q[3] = b3;
        }
        __syncthreads();

        #pragma unroll
        for (int ks = 0; ks < 2; ++ks) {
            const bf16x8 af = *(const bf16x8*)&As[wave * 16 + l16][ks * 32 + quad * 8];
            #pragma unroll
            for (int nt = 0; nt < 8; ++nt) {
                const bf16x8 bfg = *(const bf16x8*)&Bs[nt * 16 + l16][ks * 32 + quad * 8];
                acc[nt] = __builtin_amdgcn_mfma_f32_16x16x32_bf16(af, bfg, acc[nt], 0, 0, 0);
            }
        }
        __syncthreads();
    }

    const int mbase = r0 + wave * 16 + quad * 4;
    #pragma unroll
    for (int nt = 0; nt < 8; ++nt) {
        #pragma unroll
        for (int r = 0; r < 4; ++r) {
            const int m = mbase + r;
            if (m < N_NODES)
                hW[(size_t)m * HF + nt * 16 + l16] = __float2bfloat16(acc[nt][r]);
        }
    }

    const float lwv0 = lw[l16], lwv1 = lw[l16 + 16];
    const float rwv0 = rw[l16], rwv1 = rw[l16 + 16];
    const float lb0 = lb[0], rb0 = rb[0];
    #pragma unroll
    for (int r = 0; r < 4; ++r) {
        const int m = mbase + r;
        float el4[4], er4[4];
        #pragma unroll
        for (int hh = 0; hh < 4; ++hh) {
            float pl = acc[2 * hh][r] * lwv0 + acc[2 * hh + 1][r] * lwv1;
            float pr = acc[2 * hh][r] * rwv0 + acc[2 * hh + 1][r] * rwv1;
            #pragma unroll
            for (int o = 1; o < 16; o <<= 1) {
                pl += __shfl_xor(pl, o);
                pr += __shfl_xor(pr, o);
            }
            el4[hh] = pl + lb0;
            er4[hh] = pr + rb0;
        }
        if (l16 == 0 && m < N_NODES) {
            *(float4*)&el[m * H_HEADS] = make_float4(el4[0], el4[1], el4[2], el4[3]);
            *(float4*)&er[m * H_HEADS] = make_float4(er4[0], er4[1], er4[2], er4[3]);
        }
    }
}

// ---------------------------------------------------------------------------
// K5: per-node softmax + weighted gather-sum. Wave-per-node (4 nodes/block);
// lane handles 2 features via one bf16x2 load. No max pass (logits < ~8,
// fp32 exp safe; alpha identical).
// ---------------------------------------------------------------------------
__global__ __launch_bounds__(256) void k_aggregate(const __hip_bfloat16* __restrict__ hW,
                                                   const float* __restrict__ el,
                                                   const float* __restrict__ er,
                                                   const unsigned* __restrict__ off_end,
                                                   const unsigned* __restrict__ perm,
                                                   const float* __restrict__ bias,
                                                   float* __restrict__ out) {
    const int wave = threadIdx.x >> 6;
    const int lane = threadIdx.x & 63;
    const int n    = blockIdx.x * 4 + wave;        // 12500*4 = 50000 exact
    const int hh   = lane >> 4;
    const unsigned beg = (n == 0) ? 0u : off_end[n - 1];
    const unsigned end = off_end[n];
    const float eld = el[n * H_HEADS + hh];
    const unsigned* hWu = (const unsigned*)hW;     // bf16x2 view

    float a0 = 0.f, a1 = 0.f, denom = 0.f;
    unsigned j = beg;
    for (; j + 4 <= end; j += 4) {
        int s[4];
        #pragma unroll
        for (int u = 0; u < 4; ++u) s[u] = (int)perm[j + u];
        unsigned g2[4];
        float e4[4];
        #pragma unroll
        for (int u = 0; u < 4; ++u) {
            g2[u] = hWu[(size_t)s[u] * (HF / 2) + lane];
            e4[u] = er[s[u] * H_HEADS + hh];
        }
        #pragma unroll
        for (int u = 0; u < 4; ++u) {
            float v = e4[u] + eld;
            v = (v >= 0.f) ? v : NEG_SLOPE * v;
            const float p = __expf(v);
            denom += p;
            a0 += p * __uint_as_float(g2[u] << 16);
            a1 += p * __uint_as_float(g2[u] & 0xFFFF0000u);
        }
    }
    for (; j < end; ++j) {
        const int si = (int)perm[j];
        const unsigned g2 = hWu[(size_t)si * (HF / 2) + lane];
        float v = er[si * H_HEADS + hh] + eld;
        v = (v >= 0.f) ? v : NEG_SLOPE * v;
        const float p = __expf(v);
        denom += p;
        a0 += p * __uint_as_float(g2 << 16);
        a1 += p * __uint_as_float(g2 & 0xFFFF0000u);
    }
    const float inv = (end > beg) ? 1.f / denom : 0.f;
    const float2 bv = *(const float2*)&bias[lane * 2];
    float2 o2 = make_float2(a0 * inv + bv.x, a1 * inv + bv.y);
    *(float2*)&out[(size_t)n * HF + lane * 2] = o2;
}

// ---------------------------------------------------------------------------
// launch — ws (float units): el 0 / er 200k / cnt 400k / off 450k /
// perm 500k / Wt 1300k / hW 1320k..4520k  => 18.1 MB (ws-safe).
// ---------------------------------------------------------------------------
extern "C" void kernel_launch(void* const* d_in, const int* in_sizes, int n_in,
                              void* d_out, int out_size, void* d_ws, size_t ws_size,
                              hipStream_t stream) {
    const float* h    = (const float*)d_in[0];
    const float* W    = (const float*)d_in[1];
    const float* lw   = (const float*)d_in[2];
    const float* lb   = (const float*)d_in[3];
    const float* rw   = (const float*)d_in[4];
    const float* rb   = (const float*)d_in[5];
    const float* bias = (const float*)d_in[6];
    const int*   src  = (const int*)d_in[7];
    const int*   dst  = (const int*)d_in[8];
    float* out = (float*)d_out;

    float*    ws   = (float*)d_ws;
    float*    el   = ws;                           // 200,000 f
    float*    er   = ws + 200000;                  // 200,000 f
    unsigned* cnt  = (unsigned*)(ws + 400000);     //  50,000 u32
    unsigned* off  = (unsigned*)(ws + 450000);     //  50,000 u32
    unsigned* perm = (unsigned*)(ws + 500000);     // 800,000 u32
    __hip_bfloat16* Wt = (__hip_bfloat16*)(ws + 1300000);  // 32,768 bf16
    __hip_bfloat16* hW = (__hip_bfloat16*)(ws + 1320000);  // 6.4M bf16

    hipMemsetAsync(cnt, 0, N_NODES * sizeof(unsigned), stream);
    k_hist_prep<<<HIST_BLOCKS + PREP_BLOCKS, 256, 0, stream>>>(dst, cnt, W, Wt);
    k_scan<<<SCAN_BLOCKS, 256, 0, stream>>>(cnt, off);
    k_fill<<<FILL_PASSES * HIST_BLOCKS, 256, 0, stream>>>(src, dst, off, perm);
    k_gemm<<<(N_NODES + 63) / 64, 256, 0, stream>>>(h, Wt, lw, lb, rw, rb, hW, el, er);
    k_aggregate<<<N_NODES / 4, 256, 0, stream>>>(hW, el, er, off, perm, bias, out);
}

// Round 9
// 229.172 us; speedup vs baseline: 1.1509x; 1.0873x over previous
//
#include <hip/hip_runtime.h>
#include <hip/hip_bf16.h>

// Problem constants
#define N_NODES 50000
#define E_EDGES 800000
#define D_IN    256
#define H_HEADS 4
#define HF      128          // H*F
#define NEG_SLOPE 0.2f
#define SCAN_BLOCKS ((N_NODES + 255) / 256)   // 196
#define HIST_BLOCKS (E_EDGES / 256)           // 3125
#define PREP_BLOCKS 128                       // 32768 W elems / 256
#define ZERO_BLOCKS SCAN_BLOCKS               // 196
#define GEMM_BLOCKS ((N_NODES + 63) / 64)     // 782
#define FILL_PASSES 8
#define NODES_PER_PASS (N_NODES / FILL_PASSES)  // 6250

typedef __attribute__((ext_vector_type(8))) short bf16x8;   // 8 bf16 = 4 VGPRs
typedef __attribute__((ext_vector_type(4))) float f32x4;

__device__ __forceinline__ float bf_lo(unsigned u) { return __uint_as_float(u << 16); }
__device__ __forceinline__ float bf_hi(unsigned u) { return __uint_as_float(u & 0xFFFF0000u); }

// ---------------------------------------------------------------------------
// K_a: fat = [zero cnt: 196 blocks] + [prepW: 128 blocks]. Both trivial,
// no LDS, no inter-dependency. Replaces memset + standalone prepW.
// ---------------------------------------------------------------------------
__global__ __launch_bounds__(256) void k_zero_prep(unsigned* __restrict__ cnt,
                                                   const float* __restrict__ W,
                                                   __hip_bfloat16* __restrict__ Wt) {
    const int b = blockIdx.x;
    if (b < ZERO_BLOCKS) {
        const int g = b * 256 + threadIdx.x;
        if (g < N_NODES) cnt[g] = 0u;
    } else {
        const int g = (b - ZERO_BLOCKS) * 256 + threadIdx.x;  // over 32768
        const int n = g >> 8;
        const int k = g & 255;
        Wt[n * D_IN + k] = __float2bfloat16(W[k * HF + n]);
    }
}

// ---------------------------------------------------------------------------
// K_b: fat = [gemm: 782 blocks FIRST] + [hist: 3125 blocks behind].
// gemm (MFMA/LDS-bound) is the long pole -> placed first so it's resident
// from t=0; hist (atomic-latency, 0.3% VALU) fills remaining slots and
// hides inside gemm's window. No inter-dependency (R7 lesson: only fuse
// independent roles; LDS cost borne by both -> hist at 5 blocks/CU, ample
// for atomic issue).
// ---------------------------------------------------------------------------
__global__ __launch_bounds__(256) void k_gemm_hist(const float* __restrict__ h,
                                                   const __hip_bfloat16* __restrict__ Wt,
                                                   const float* __restrict__ lw,
                                                   const float* __restrict__ lb,
                                                   const float* __restrict__ rw,
                                                   const float* __restrict__ rb,
                                                   __hip_bfloat16* __restrict__ hW,
                                                   float* __restrict__ el,
                                                   float* __restrict__ er,
                                                   const int* __restrict__ dst,
                                                   unsigned* __restrict__ cnt) {
    __shared__ __hip_bfloat16 As[64][72];
    __shared__ __hip_bfloat16 Bs[128][72];

    if (blockIdx.x >= GEMM_BLOCKS) {
        // ---- hist role ----
        const int g = (blockIdx.x - GEMM_BLOCKS) * 256 + threadIdx.x;  // over E
        atomicAdd(&cnt[dst[g]], 1u);
        return;
    }

    // ---- gemm role ----
    const int t    = threadIdx.x;
    const int r0   = blockIdx.x * 64;
    const int wave = t >> 6;
    const int lane = t & 63;
    const int l16  = lane & 15;
    const int quad = lane >> 4;

    f32x4 acc[8] = {};

    for (int k0 = 0; k0 < D_IN; k0 += 64) {
        {   // stage A: 64 rows x 64 k, fp32 -> bf16
            const int row  = t >> 2;
            const int koff = (t & 3) * 16;
            const int n    = r0 + row;
            float v[16];
            if (n < N_NODES) {
                const float* p = h + (size_t)n * D_IN + k0 + koff;
                *(float4*)&v[0]  = ((const float4*)p)[0];
                *(float4*)&v[4]  = ((const float4*)p)[1];
                *(float4*)&v[8]  = ((const float4*)p)[2];
                *(float4*)&v[12] = ((const float4*)p)[3];
            } else {
                #pragma unroll
                for (int i = 0; i < 16; ++i) v[i] = 0.f;
            }
            __hip_bfloat16 b[16];
            #pragma unroll
            for (int i = 0; i < 16; ++i) b[i] = __float2bfloat16(v[i]);
            *(uint4*)&As[row][koff]     = ((uint4*)b)[0];
            *(uint4*)&As[row][koff + 8] = ((uint4*)b)[1];
        }
        {   // stage B: 128 n-rows x 64 k from Wt (bf16)
            const int n    = t >> 1;
            const int koff = (t & 1) * 32;
            const uint4* p = (const uint4*)(Wt + n * D_IN + k0 + koff);
            uint4 b0 = p[0], b1 = p[1], b2 = p[2], b3 = p[3];
            uint4* q = (uint4*)&Bs[n][koff];
            q[0] = b0; q[1] = b1; q[2] = b2; q[3] = b3;
        }
        __syncthreads();

        #pragma unroll
        for (int ks = 0; ks < 2; ++ks) {
            const bf16x8 af = *(const bf16x8*)&As[wave * 16 + l16][ks * 32 + quad * 8];
            #pragma unroll
            for (int nt = 0; nt < 8; ++nt) {
                const bf16x8 bfg = *(const bf16x8*)&Bs[nt * 16 + l16][ks * 32 + quad * 8];
                acc[nt] = __builtin_amdgcn_mfma_f32_16x16x32_bf16(af, bfg, acc[nt], 0, 0, 0);
            }
        }
        __syncthreads();
    }

    const int mbase = r0 + wave * 16 + quad * 4;
    #pragma unroll
    for (int nt = 0; nt < 8; ++nt) {
        #pragma unroll
        for (int r = 0; r < 4; ++r) {
            const int m = mbase + r;
            if (m < N_NODES)
                hW[(size_t)m * HF + nt * 16 + l16] = __float2bfloat16(acc[nt][r]);
        }
    }

    const float lwv0 = lw[l16], lwv1 = lw[l16 + 16];
    const float rwv0 = rw[l16], rwv1 = rw[l16 + 16];
    const float lb0 = lb[0], rb0 = rb[0];
    #pragma unroll
    for (int r = 0; r < 4; ++r) {
        const int m = mbase + r;
        float el4[4], er4[4];
        #pragma unroll
        for (int hh = 0; hh < 4; ++hh) {
            float pl = acc[2 * hh][r] * lwv0 + acc[2 * hh + 1][r] * lwv1;
            float pr = acc[2 * hh][r] * rwv0 + acc[2 * hh + 1][r] * rwv1;
            #pragma unroll
            for (int o = 1; o < 16; o <<= 1) {
                pl += __shfl_xor(pl, o);
                pr += __shfl_xor(pr, o);
            }
            el4[hh] = pl + lb0;
            er4[hh] = pr + rb0;
        }
        if (l16 == 0 && m < N_NODES) {
            *(float4*)&el[m * H_HEADS] = make_float4(el4[0], el4[1], el4[2], el4[3]);
            *(float4*)&er[m * H_HEADS] = make_float4(er4[0], er4[1], er4[2], er4[3]);
        }
    }
}

// ---------------------------------------------------------------------------
// merged scan: block b reduces cnt[0..b*256) cooperatively, then LDS-scans
// its own 256 elems.
// ---------------------------------------------------------------------------
__global__ __launch_bounds__(256) void k_scan(const unsigned* __restrict__ cnt,
                                              unsigned* __restrict__ off) {
    __shared__ unsigned s[256];
    const int t = threadIdx.x;
    const int b = blockIdx.x;
    const int base = b * 256;

    unsigned part = 0;
    #pragma unroll 4
    for (int i = t; i < base; i += 256) part += cnt[i];
    s[t] = part;
    __syncthreads();
    #pragma unroll
    for (int o = 128; o > 0; o >>= 1) {
        if (t < o) s[t] += s[t + o];
        __syncthreads();
    }
    const unsigned pre = s[0];
    __syncthreads();

    const int g = base + t;
    const unsigned x = (g < N_NODES) ? cnt[g] : 0u;
    s[t] = x;
    __syncthreads();
    unsigned inc = x;
    #pragma unroll
    for (int o = 1; o < 256; o <<= 1) {
        const unsigned v = (t >= o) ? s[t - o] : 0u;
        __syncthreads();
        inc += v;
        s[t] = inc;
        __syncthreads();
    }
    if (g < N_NODES) off[g] = pre + inc - x;   // exclusive
}

// ---------------------------------------------------------------------------
// K_fill: dst-range multi-pass scatter (write-window clustering for perm).
// ---------------------------------------------------------------------------
__global__ __launch_bounds__(256) void k_fill(const int* __restrict__ src,
                                              const int* __restrict__ dst,
                                              unsigned* __restrict__ off,
                                              unsigned* __restrict__ perm) {
    const int pass  = blockIdx.x / HIST_BLOCKS;
    const int chunk = blockIdx.x - pass * HIST_BLOCKS;
    const int g = chunk * 256 + threadIdx.x;        // over E (exact)
    const int d = dst[g];
    const int lo = pass * NODES_PER_PASS;
    if ((unsigned)(d - lo) < (unsigned)NODES_PER_PASS) {
        const unsigned p = atomicAdd(&off[d], 1u);
        perm[p] = (unsigned)src[g];
    }
}

// ---------------------------------------------------------------------------
// K5: per-node softmax + weighted gather-sum. Wave-per-node, 2 edges/wave:
// half = lane>>5 picks even/odd edge; lane&31 owns 4 features (8 B load);
// halves combined via shfl_xor(...,32) at the end. Per-edge exp/leaky/er
// redundancy halved vs 1-edge/wave. No max pass (logits < ~8, fp32 safe).
// ---------------------------------------------------------------------------
__global__ __launch_bounds__(256) void k_aggregate(const __hip_bfloat16* __restrict__ hW,
                                                   const float* __restrict__ el,
                                                   const float* __restrict__ er,
                                                   const unsigned* __restrict__ off_end,
                                                   const unsigned* __restrict__ perm,
                                                   const float* __restrict__ bias,
                                                   float* __restrict__ out) {
    const int wave = threadIdx.x >> 6;
    const int lane = threadIdx.x & 63;
    const int half = lane >> 5;                    // 0: even edge, 1: odd edge
    const int l    = lane & 31;                    // features 4*l .. 4*l+3
    const int hh   = l >> 3;
    const int n    = blockIdx.x * 4 + wave;        // 12500*4 = 50000 exact
    const unsigned beg = (n == 0) ? 0u : off_end[n - 1];
    const unsigned end = off_end[n];
    const float eld = el[(unsigned)n * H_HEADS + hh];
    const uint2* hW2 = (const uint2*)hW;           // 8B granules: row = 32

    float a0 = 0.f, a1 = 0.f, a2 = 0.f, a3 = 0.f, denom = 0.f;
    unsigned j = beg;
    for (; j + 4 <= end; j += 4) {                 // 4 edges per step
        const unsigned s0 = perm[j + half];
        const unsigned s1 = perm[j + 2 + half];
        const float er0 = er[s0 * H_HEADS + hh];
        const float er1 = er[s1 * H_HEADS + hh];
        const uint2 g0 = hW2[s0 * 32u + l];
        const uint2 g1 = hW2[s1 * 32u + l];
        float v0 = er0 + eld; v0 = (v0 >= 0.f) ? v0 : NEG_SLOPE * v0;
        float v1 = er1 + eld; v1 = (v1 >= 0.f) ? v1 : NEG_SLOPE * v1;
        const float p0 = __expf(v0);
        const float p1 = __expf(v1);
        denom += p0 + p1;
        a0 += p0 * bf_lo(g0.x) + p1 * bf_lo(g1.x);
        a1 += p0 * bf_hi(g0.x) + p1 * bf_hi(g1.x);
        a2 += p0 * bf_lo(g0.y) + p1 * bf_lo(g1.y);
        a3 += p0 * bf_hi(g0.y) + p1 * bf_hi(g1.y);
    }
    for (; j < end; j += 2) {                      // tail: 1..3 edges
        const unsigned i = j + half;
        const bool ok = (i < end);
        const unsigned s = ok ? perm[i] : 0u;
        const float erv = er[s * H_HEADS + hh];
        const uint2 g = hW2[s * 32u + l];
        float v = erv + eld; v = (v >= 0.f) ? v : NEG_SLOPE * v;
        const float p = ok ? __expf(v) : 0.f;
        denom += p;
        a0 += p * bf_lo(g.x);
        a1 += p * bf_hi(g.x);
        a2 += p * bf_lo(g.y);
        a3 += p * bf_hi(g.y);
    }
    // combine even/odd halves
    denom += __shfl_xor(denom, 32);
    a0 += __shfl_xor(a0, 32);
    a1 += __shfl_xor(a1, 32);
    a2 += __shfl_xor(a2, 32);
    a3 += __shfl_xor(a3, 32);
    if (half == 0) {
        const float inv = (end > beg) ? 1.f / denom : 0.f;
        const float4 bv = *(const float4*)&bias[l * 4];
        float4 o = make_float4(a0 * inv + bv.x, a1 * inv + bv.y,
                               a2 * inv + bv.z, a3 * inv + bv.w);
        *(float4*)&out[(unsigned)n * HF + l * 4] = o;
    }
}

// ---------------------------------------------------------------------------
// launch — ws (float units): el 0 / er 200k / cnt 400k / off 450k /
// perm 500k / Wt 1300k / hW 1320k..4520k  => 18.1 MB (ws-safe).
// 5 dispatches: [zero|prepW] -> [gemm|hist] -> scan -> fill -> aggregate.
// ---------------------------------------------------------------------------
extern "C" void kernel_launch(void* const* d_in, const int* in_sizes, int n_in,
                              void* d_out, int out_size, void* d_ws, size_t ws_size,
                              hipStream_t stream) {
    const float* h    = (const float*)d_in[0];
    const float* W    = (const float*)d_in[1];
    const float* lw   = (const float*)d_in[2];
    const float* lb   = (const float*)d_in[3];
    const float* rw   = (const float*)d_in[4];
    const float* rb   = (const float*)d_in[5];
    const float* bias = (const float*)d_in[6];
    const int*   src  = (const int*)d_in[7];
    const int*   dst  = (const int*)d_in[8];
    float* out = (float*)d_out;

    float*    ws   = (float*)d_ws;
    float*    el   = ws;                           // 200,000 f
    float*    er   = ws + 200000;                  // 200,000 f
    unsigned* cnt  = (unsigned*)(ws + 400000);     //  50,000 u32
    unsigned* off  = (unsigned*)(ws + 450000);     //  50,000 u32
    unsigned* perm = (unsigned*)(ws + 500000);     // 800,000 u32
    __hip_bfloat16* Wt = (__hip_bfloat16*)(ws + 1300000);  // 32,768 bf16
    __hip_bfloat16* hW = (__hip_bfloat16*)(ws + 1320000);  // 6.4M bf16

    k_zero_prep<<<ZERO_BLOCKS + PREP_BLOCKS, 256, 0, stream>>>(cnt, W, Wt);
    k_gemm_hist<<<GEMM_BLOCKS + HIST_BLOCKS, 256, 0, stream>>>(
        h, Wt, lw, lb, rw, rb, hW, el, er, dst, cnt);
    k_scan<<<SCAN_BLOCKS, 256, 0, stream>>>(cnt, off);
    k_fill<<<FILL_PASSES * HIST_BLOCKS, 256, 0, stream>>>(src, dst, off, perm);
    k_aggregate<<<N_NODES / 4, 256, 0, stream>>>(hW, el, er, off, perm, bias, out);
}